// Round 2
// baseline (70611.853 us; speedup 1.0000x reference)
//
#include <hip/hip_runtime.h>

// DARTS recurrent cell, MI355X bf16-MFMA.
// Persistent single-kernel time loop: 256 blocks x 512 threads (1 block/CU),
// hand-rolled device-scope grid barrier between phases (5 per timestep).
// Barrier spin is BOUNDED (poison latch) -> kernel cannot hang.
// T=256, B=256, NINP=NHID=1024. Output: [T,B,1024] fp32.

typedef short short8 __attribute__((ext_vector_type(8)));
typedef float floatx4 __attribute__((ext_vector_type(4)));

#define MFMA __builtin_amdgcn_mfma_f32_16x16x32_bf16

enum { ACT_SIG = 0, ACT_RELU = 1, ACT_TANH = 2, ACT_ID = 3 };

__device__ __forceinline__ unsigned short f2bf(float f) {
  unsigned u = __builtin_bit_cast(unsigned, f);
  u += 0x7fffu + ((u >> 16) & 1u);   // round-to-nearest-even
  return (unsigned short)(u >> 16);
}

__device__ __forceinline__ float sigf(float z) { return 1.f / (1.f + __expf(-z)); }

__device__ __forceinline__ float actf(int a, float h) {
  if (a == ACT_SIG)  return sigf(h);
  if (a == ACT_RELU) return fmaxf(h, 0.f);
  if (a == ACT_TANH) return 1.f - 2.f / (__expf(2.f * h) + 1.f);
  return h;
}

// ---------------- device-scope grid barrier (bounded spin) ----------------
// Monotonic counter in d_ws. Each block adds 1 per sync; target grows by
// gridDim per sync. Release-add writes back this XCD's L2; acquire fence
// after the spin invalidates L1/L2 before subsequent reads.
// skip_wait: once a block has ever timed out, it keeps adding but never
// waits again -> global forward progress is guaranteed.
__device__ __forceinline__ bool grid_sync(unsigned* bar, unsigned target,
                                          bool skip_wait) {
  __shared__ int gs_flag;
  __syncthreads();   // all waves of block done with phase (vm drained)
  if (threadIdx.x == 0) {
    __hip_atomic_fetch_add(bar, 1u, __ATOMIC_RELEASE, __HIP_MEMORY_SCOPE_AGENT);
    int ok = 1;
    if (!skip_wait) {
      int spins = 0;
      while (__hip_atomic_load(bar, __ATOMIC_RELAXED,
                               __HIP_MEMORY_SCOPE_AGENT) < target) {
        __builtin_amdgcn_s_sleep(16);          // ~0.5 us poll granularity
        if (++spins > (1 << 19)) { ok = 0; break; }  // ~0.25 s cap
      }
    }
    gs_flag = ok;
  }
  __syncthreads();
  __builtin_amdgcn_fence(__ATOMIC_ACQUIRE, "agent");
  return gs_flag != 0;
}

// ---------------- generic 2-output GEMM tile ----------------
// out = base + sigmoid(c)*(act(h) - base), [c|h] = A @ W.
// A bf16 [256][K]; Wt bf16 [2048][K] n-major (c rows 0..1023, h rows 1024..2047).
// Tile: 32 m-rows x (NB*16) state-cols. DEPTH-stage global prefetch.
template <int NB, int DEPTH>
__device__ __forceinline__ void g2_tile(
    const unsigned short* __restrict__ A, const unsigned short* __restrict__ Wt,
    const float* __restrict__ base, float* __restrict__ out_f,
    unsigned short* __restrict__ out_b, int act, int K, int m0, int sc0,
    int lane) {
  const int col = lane & 15, quad = lane >> 4;
  const unsigned short* pa0 = A + (size_t)(m0 + col) * K + quad * 8;
  const unsigned short* pa1 = pa0 + (size_t)16 * K;
  const unsigned short* pbc[NB];
  const unsigned short* pbh[NB];
#pragma unroll
  for (int j = 0; j < NB; ++j) {
    pbc[j] = Wt + (size_t)(sc0 + 16 * j + col) * K + quad * 8;
    pbh[j] = Wt + (size_t)(1024 + sc0 + 16 * j + col) * K + quad * 8;
  }

  floatx4 ac[2][NB], ah[2][NB];
#pragma unroll
  for (int i = 0; i < 2; ++i)
#pragma unroll
    for (int j = 0; j < NB; ++j) {
      ac[i][j] = (floatx4){0.f, 0.f, 0.f, 0.f};
      ah[i][j] = (floatx4){0.f, 0.f, 0.f, 0.f};
    }

  short8 ra0[DEPTH], ra1[DEPTH], rbc[DEPTH][NB], rbh[DEPTH][NB];

#define G2_LD(s, k)                                                            \
  {                                                                            \
    ra0[s] = *(const short8*)(pa0 + (k));                                      \
    ra1[s] = *(const short8*)(pa1 + (k));                                      \
    _Pragma("unroll") for (int j = 0; j < NB; ++j) {                           \
      rbc[s][j] = *(const short8*)(pbc[j] + (k));                              \
      rbh[s][j] = *(const short8*)(pbh[j] + (k));                              \
    }                                                                          \
  }
#define G2_MM(s)                                                               \
  {                                                                            \
    _Pragma("unroll") for (int j = 0; j < NB; ++j) {                           \
      ac[0][j] = MFMA(ra0[s], rbc[s][j], ac[0][j], 0, 0, 0);                   \
      ac[1][j] = MFMA(ra1[s], rbc[s][j], ac[1][j], 0, 0, 0);                   \
      ah[0][j] = MFMA(ra0[s], rbh[s][j], ah[0][j], 0, 0, 0);                   \
      ah[1][j] = MFMA(ra1[s], rbh[s][j], ah[1][j], 0, 0, 0);                   \
    }                                                                          \
  }

#pragma unroll
  for (int s = 0; s < DEPTH; ++s) G2_LD(s, s * 32);
  for (int k = DEPTH * 32; k < K; k += DEPTH * 32) {
#pragma unroll
    for (int s = 0; s < DEPTH; ++s) {
      G2_MM(s);
      G2_LD(s, k + s * 32);
    }
  }
#pragma unroll
  for (int s = 0; s < DEPTH; ++s) G2_MM(s);
#undef G2_LD
#undef G2_MM

#pragma unroll
  for (int mi = 0; mi < 2; ++mi)
#pragma unroll
    for (int j = 0; j < NB; ++j)
#pragma unroll
      for (int rr = 0; rr < 4; ++rr) {
        int m = m0 + mi * 16 + quad * 4 + rr;
        int n = sc0 + j * 16 + col;
        int idx = m * 1024 + n;
        float c = ac[mi][j][rr];
        float h = ah[mi][j][rr];
        float p = base[idx];
        float v = fmaf(sigf(c), actf(act, h) - p, p);
        out_f[idx] = v;
        if (out_b) out_b[idx] = f2bf(v);
      }
}

// ---------------- phase E tile: s6 & s8 (both from s5) + mean + next prep ---
// Tile: 32 m-rows x 16 state-cols, two weight matrices.
__device__ __forceinline__ void e_tile(
    const unsigned short* __restrict__ A, const unsigned short* __restrict__ W5t,
    const unsigned short* __restrict__ W7t, const float* __restrict__ m1,
    const float* __restrict__ m2, const float* __restrict__ m3,
    const float* __restrict__ m4, const float* __restrict__ m5,
    const float* __restrict__ m7, const float* __restrict__ xnext,
    float* __restrict__ out_t, unsigned short* __restrict__ xhb,
    int m0, int sc0, int lane) {
  const int col = lane & 15, quad = lane >> 4;
  const int K = 1024;
  const unsigned short* pa0 = A + (size_t)(m0 + col) * K + quad * 8;
  const unsigned short* pa1 = pa0 + (size_t)16 * K;
  const unsigned short* pu0 = W5t + (size_t)(sc0 + col) * K + quad * 8;
  const unsigned short* pu1 = W5t + (size_t)(1024 + sc0 + col) * K + quad * 8;
  const unsigned short* pv0 = W7t + (size_t)(sc0 + col) * K + quad * 8;
  const unsigned short* pv1 = W7t + (size_t)(1024 + sc0 + col) * K + quad * 8;

  floatx4 c6[2], h6[2], c8[2], h8[2];
#pragma unroll
  for (int i = 0; i < 2; ++i) {
    c6[i] = (floatx4){0.f, 0.f, 0.f, 0.f};
    h6[i] = (floatx4){0.f, 0.f, 0.f, 0.f};
    c8[i] = (floatx4){0.f, 0.f, 0.f, 0.f};
    h8[i] = (floatx4){0.f, 0.f, 0.f, 0.f};
  }

  short8 ra0[2], ra1[2], ru0[2], ru1[2], rv0[2], rv1[2];
#define E_LD(s, k)                              \
  {                                             \
    ra0[s] = *(const short8*)(pa0 + (k));       \
    ra1[s] = *(const short8*)(pa1 + (k));       \
    ru0[s] = *(const short8*)(pu0 + (k));       \
    ru1[s] = *(const short8*)(pu1 + (k));       \
    rv0[s] = *(const short8*)(pv0 + (k));       \
    rv1[s] = *(const short8*)(pv1 + (k));       \
  }
#define E_MM(s)                                 \
  {                                             \
    c6[0] = MFMA(ra0[s], ru0[s], c6[0], 0, 0, 0); \
    c6[1] = MFMA(ra1[s], ru0[s], c6[1], 0, 0, 0); \
    h6[0] = MFMA(ra0[s], ru1[s], h6[0], 0, 0, 0); \
    h6[1] = MFMA(ra1[s], ru1[s], h6[1], 0, 0, 0); \
    c8[0] = MFMA(ra0[s], rv0[s], c8[0], 0, 0, 0); \
    c8[1] = MFMA(ra1[s], rv0[s], c8[1], 0, 0, 0); \
    h8[0] = MFMA(ra0[s], rv1[s], h8[0], 0, 0, 0); \
    h8[1] = MFMA(ra1[s], rv1[s], h8[1], 0, 0, 0); \
  }

  E_LD(0, 0);
  E_LD(1, 32);
  for (int k = 64; k < K; k += 64) {
    E_MM(0);
    E_LD(0, k);
    E_MM(1);
    E_LD(1, k + 32);
  }
  E_MM(0);
  E_MM(1);
#undef E_LD
#undef E_MM

#pragma unroll
  for (int mi = 0; mi < 2; ++mi)
#pragma unroll
    for (int rr = 0; rr < 4; ++rr) {
      int m = m0 + mi * 16 + quad * 4 + rr;
      int n = sc0 + col;
      int idx = m * 1024 + n;
      float b = m5[idx];
      float s6 = fmaf(sigf(c6[mi][rr]), sigf(h6[mi][rr]) - b, b);
      float s8 = fmaf(sigf(c8[mi][rr]), fmaxf(h8[mi][rr], 0.f) - b, b);
      float sum = m1[idx] + m2[idx] + m3[idx] + m4[idx] + b + m7[idx] + s6 + s8;
      float hh = sum * 0.125f;
      out_t[idx] = hh;
      xhb[m * 2048 + 1024 + n] = f2bf(hh);
      xhb[m * 2048 + n] = f2bf(xnext[idx]);
    }
}

// ---------------- persistent time-loop kernel ----------------
__global__ __launch_bounds__(512, 2) void darts_persist(
    const float* __restrict__ x_all, const float* __restrict__ h0,
    const unsigned short* __restrict__ wtb, float* out, float* __restrict__ smb,
    unsigned short* __restrict__ sbb, unsigned short* __restrict__ xhb,
    unsigned* __restrict__ bar) {
  const size_t BH = (size_t)256 * 1024;
  const int lane = threadIdx.x & 63;
  const int wave = threadIdx.x >> 6;   // 0..7
  const int blk = blockIdx.x;          // 0..255

#define WTS(i) (wtb + (size_t)2048 * 2048 + (size_t)(i) * 2048 * 1024)
  float* sm0 = smb;                 // s0
  float* sm1 = smb + 1 * BH;        // s1
  float* sm2 = smb + 2 * BH;        // s2
  float* sm3 = smb + 3 * BH;        // s3
  float* sm4 = smb + 4 * BH;        // s4
  float* sm5 = smb + 5 * BH;        // s5
  float* sm6 = smb + 6 * BH;        // s7
  unsigned short* sb0 = sbb;            // bf16 s0
  unsigned short* sb1 = sbb + 1 * BH;   // bf16 s1
  unsigned short* sb2 = sbb + 2 * BH;   // bf16 s2
  unsigned short* sb3 = sbb + 3 * BH;   // bf16 s3
  unsigned short* sb4 = sbb + 4 * BH;   // bf16 s5

  bool poisoned = false;
  unsigned tgt = 0;
  for (int t = 0; t < 256; ++t) {
    const float* hp = (t == 0) ? h0 : (out + (size_t)(t - 1) * BH);
    float* o_t = out + (size_t)t * BH;
    const float* xnext = x_all + (size_t)((t < 255) ? t + 1 : 255) * BH;

    // P0: s0 = h + sig(c)*(tanh(h') - h), [c|h'] = [x,h] @ W0, K=2048
    if (wave < 2) {
      int tau = wave * 256 + blk;    // 512 tiles: 8 m-tiles x 64 sc-tiles
      g2_tile<1, 4>(xhb, wtb, hp, sm0, sb0, ACT_TANH, 2048,
                    (tau >> 6) * 32, (tau & 63) * 16, lane);
    }
    tgt += 256; poisoned |= !grid_sync(bar, tgt, poisoned);

    // P1: s1 = upd(s0, Ws[0], sigmoid)
    if (wave < 2) {
      int tau = wave * 256 + blk;
      g2_tile<1, 4>(sb0, WTS(0), sm0, sm1, sb1, ACT_SIG, 1024,
                    (tau >> 6) * 32, (tau & 63) * 16, lane);
    }
    tgt += 256; poisoned |= !grid_sync(bar, tgt, poisoned);

    // P2: s2 = upd(s1, Ws[1], relu); s3 = upd(s1, Ws[2], relu);
    //     s4 = upd(s1, Ws[3], id)        (job == wave, 256 tiles each)
    if (wave < 3) {
      const unsigned short* W = (wave == 0) ? WTS(1) : (wave == 1) ? WTS(2) : WTS(3);
      float* of = (wave == 0) ? sm2 : (wave == 1) ? sm3 : sm4;
      unsigned short* ob = (wave == 0) ? sb2 : (wave == 1) ? sb3 : (unsigned short*)nullptr;
      int act = (wave == 2) ? ACT_ID : ACT_RELU;
      g2_tile<2, 2>(sb1, W, sm1, of, ob, act, 1024,
                    (blk >> 5) * 32, (blk & 31) * 32, lane);
    }
    tgt += 256; poisoned |= !grid_sync(bar, tgt, poisoned);

    // P3: s5 = upd(s2, Ws[4], tanh); s7 = upd(s3, Ws[6], tanh)
    if (wave < 2) {
      const unsigned short* Aop = (wave == 0) ? sb2 : sb3;
      const unsigned short* W = (wave == 0) ? WTS(4) : WTS(6);
      const float* bs = (wave == 0) ? sm2 : sm3;
      float* of = (wave == 0) ? sm5 : sm6;
      unsigned short* ob = (wave == 0) ? sb4 : (unsigned short*)nullptr;
      g2_tile<2, 2>(Aop, W, bs, of, ob, ACT_TANH, 1024,
                    (blk >> 5) * 32, (blk & 31) * 32, lane);
    }
    tgt += 256; poisoned |= !grid_sync(bar, tgt, poisoned);

    // P4: s6 = upd(s5, Ws[5], sigmoid); s8 = upd(s5, Ws[7], relu);
    //     h = mean(s1..s8); prep xhb for next step
    if (wave < 2) {
      int tau = wave * 256 + blk;
      e_tile(sb4, WTS(5), WTS(7), sm1, sm2, sm3, sm4, sm5, sm6,
             xnext, o_t, xhb, (tau >> 6) * 32, (tau & 63) * 16, lane);
    }
    tgt += 256; poisoned |= !grid_sync(bar, tgt, poisoned);
  }
#undef WTS
}

// ---------------- weight conversion fp32 -> bf16 transposed [n][k] ----------
__global__ __launch_bounds__(256) void conv_w(const float* __restrict__ W0,
                                              const float* __restrict__ Wsrc,
                                              unsigned short* __restrict__ wt) {
  int job = blockIdx.z;
  int K = (job == 0) ? 2048 : 1024;
  int kt = blockIdx.y;
  if (kt * 32 >= K) return;
  int nt = blockIdx.x;
  const float* W = (job == 0) ? W0 : (Wsrc + (size_t)(job - 1) * 1024 * 2048);
  unsigned short* Wt = (job == 0) ? wt
      : (wt + (size_t)2048 * 2048 + (size_t)(job - 1) * 2048 * 1024);

  __shared__ unsigned short tile[32][33];
  int tx = threadIdx.x & 31;
  int ty = threadIdx.x >> 5;  // 0..7
#pragma unroll
  for (int i = 0; i < 4; ++i) {
    int k = kt * 32 + ty + i * 8;
    tile[ty + i * 8][tx] = f2bf(W[(size_t)k * 2048 + nt * 32 + tx]);
  }
  __syncthreads();
#pragma unroll
  for (int i = 0; i < 4; ++i) {
    int n = nt * 32 + ty + i * 8;
    Wt[(size_t)n * K + kt * 32 + tx] = tile[tx][ty + i * 8];
  }
}

// ---------------- init: xhb = [bf16(x0) | bf16(h0)] ----------
__global__ __launch_bounds__(256) void init_xh(const float* __restrict__ x0,
                                               const float* __restrict__ h0,
                                               unsigned short* __restrict__ xhb) {
  int i = blockIdx.x * 256 + threadIdx.x;  // 0..262143
  int m = i >> 10, n = i & 1023;
  xhb[m * 2048 + n] = f2bf(x0[i]);
  xhb[m * 2048 + 1024 + n] = f2bf(h0[i]);
}

__global__ void zero_bar(unsigned* bar) { *bar = 0u; }

extern "C" void kernel_launch(void* const* d_in, const int* in_sizes, int n_in,
                              void* d_out, int out_size, void* d_ws, size_t ws_size,
                              hipStream_t stream) {
  const float* x_all = (const float*)d_in[0];  // [256,256,1024]
  const float* h0    = (const float*)d_in[1];  // [256,1024]
  const float* W0    = (const float*)d_in[2];  // [2048,2048]
  const float* Ws    = (const float*)d_in[3];  // [8,1024,2048]
  float* out = (float*)d_out;                  // [256,256,1024]

  const size_t BH = (size_t)256 * 1024;

  // ws layout: Wt (41.94 MB) | masters fp32 s0..s5,s7 (7 MB) |
  // sb bf16 s0,s1,s2,s3,s5 (2.62 MB) | xhb bf16 (1.05 MB) | barrier (4 B)
  unsigned short* wt0 = (unsigned short*)d_ws;
  float* smbase = (float*)((char*)d_ws +
      (size_t)(2048 * 2048 + 8 * 2048 * 1024) * 2);
  unsigned short* sbbase = (unsigned short*)(smbase + (size_t)7 * BH);
  unsigned short* xhb = sbbase + (size_t)5 * BH;  // [256][2048]
  unsigned* bar = (unsigned*)(xhb + (size_t)256 * 2048);

  conv_w<<<dim3(64, 64, 9), 256, 0, stream>>>(W0, Ws, wt0);
  init_xh<<<dim3(1024), 256, 0, stream>>>(x_all, h0, xhb);
  zero_bar<<<dim3(1), dim3(1), 0, stream>>>(bar);
  darts_persist<<<dim3(256), dim3(512), 0, stream>>>(
      x_all, h0, wt0, out, smbase, sbbase, xhb, bar);
}